// Round 1
// baseline (526.274 us; speedup 1.0000x reference)
//
#include <hip/hip_runtime.h>
#include <hip/hip_bf16.h>
#include <math.h>

typedef __attribute__((ext_vector_type(4))) float floatx4;
typedef __attribute__((ext_vector_type(8))) __bf16 bf16x8;

__device__ __forceinline__ unsigned short f2bf(float f) {
    union { float f; unsigned int u; } v; v.f = f;
    unsigned int u = v.u;
    u += 0x7FFFu + ((u >> 16) & 1u);          // round-to-nearest-even
    return (unsigned short)(u >> 16);
}

// ---------------------------------------------------------------- cast kernel
__global__ void cast_f32_bf16(const float* __restrict__ in,
                              unsigned short* __restrict__ out, int n) {
    int i = (blockIdx.x * blockDim.x + threadIdx.x) * 4;
    if (i + 4 <= n) {
        float4 f = *(const float4*)(in + i);
        ushort4 o;
        o.x = f2bf(f.x); o.y = f2bf(f.y); o.z = f2bf(f.z); o.w = f2bf(f.w);
        *(ushort4*)(out + i) = o;
    }
}

// ---------------------------------------------------------------- GEMM (NT)
// C[M,N] = A[M,K] * B[N,K]^T + bias[N]
// MODE 0: store fp32 to Cf.   MODE 1: scatter bf16 to q/k/vT (N==6144 path).
#define BM 128
#define BN 128
#define BK 32
#define GPAD 8

template<int MODE>
__global__ __launch_bounds__(256) void gemm_nt(
    const unsigned short* __restrict__ A,
    const unsigned short* __restrict__ B,
    const float* __restrict__ bias,
    float* __restrict__ Cf,
    unsigned short* __restrict__ q_ws,
    unsigned short* __restrict__ k_ws,
    unsigned short* __restrict__ vT_ws,
    int M, int N, int K)
{
    __shared__ unsigned short Asm[BM][BK + GPAD];
    __shared__ unsigned short Bsm[BN][BK + GPAD];

    const int bx = blockIdx.x, by = blockIdx.y;
    const int m0 = by * BM, n0 = bx * BN;
    const int tid = threadIdx.x;
    const int lane = tid & 63, wid = tid >> 6;
    const int quad = lane >> 4, li = lane & 15;
    const int wy = wid >> 1, wx = wid & 1;

    floatx4 acc[4][4] = {};

    const int kTiles = K / BK;
    for (int kt = 0; kt < kTiles; ++kt) {
        const int k0 = kt * BK;
        // stage A and B tiles: 512 16B-chunks each, 2 per thread
        #pragma unroll
        for (int c = 0; c < 2; ++c) {
            int chunk = c * 256 + tid;            // 0..511
            int row = chunk >> 2;                 // 0..127
            int cc  = (chunk & 3) * 8;            // 0,8,16,24
            uint4 da = *(const uint4*)(A + (size_t)(m0 + row) * K + k0 + cc);
            *(uint4*)(&Asm[row][cc]) = da;
            uint4 db = *(const uint4*)(B + (size_t)(n0 + row) * K + k0 + cc);
            *(uint4*)(&Bsm[row][cc]) = db;
        }
        __syncthreads();

        bf16x8 af[4], bfr[4];
        #pragma unroll
        for (int t = 0; t < 4; ++t) {
            af[t]  = *(const bf16x8*)(&Asm[wy * 64 + t * 16 + li][quad * 8]);
            bfr[t] = *(const bf16x8*)(&Bsm[wx * 64 + t * 16 + li][quad * 8]);
        }
        #pragma unroll
        for (int i = 0; i < 4; ++i)
            #pragma unroll
            for (int j = 0; j < 4; ++j)
                acc[i][j] = __builtin_amdgcn_mfma_f32_16x16x32_bf16(
                    af[i], bfr[j], acc[i][j], 0, 0, 0);
        __syncthreads();
    }

    // ---------------- epilogue
    if (MODE == 0) {
        #pragma unroll
        for (int i = 0; i < 4; ++i)
            #pragma unroll
            for (int j = 0; j < 4; ++j) {
                int col = wx * 64 + j * 16 + li;
                float bv = bias[n0 + col];
                #pragma unroll
                for (int r = 0; r < 4; ++r) {
                    int row = wy * 64 + i * 16 + quad * 4 + r;
                    Cf[(size_t)(m0 + row) * N + n0 + col] = acc[i][j][r] + bv;
                }
            }
    } else {
        // N = 6144 layout: bx in [0,48): which = bx>>4, h = bx&15, d = col
        const int which = bx >> 4;
        const int h = bx & 15;
        const int b = by >> 4;
        const int lbase = (by & 15) * BM;
        const size_t bh = (size_t)(b * 16 + h);
        #pragma unroll
        for (int i = 0; i < 4; ++i)
            #pragma unroll
            for (int j = 0; j < 4; ++j) {
                int col = wx * 64 + j * 16 + li;   // == d
                float bv = bias[n0 + col];
                #pragma unroll
                for (int r = 0; r < 4; ++r) {
                    int row = wy * 64 + i * 16 + quad * 4 + r;
                    int l = lbase + row;
                    unsigned short ob = f2bf(acc[i][j][r] + bv);
                    if (which == 0)      q_ws[(bh * 2048 + l) * 128 + col] = ob;
                    else if (which == 1) k_ws[(bh * 2048 + l) * 128 + col] = ob;
                    else                 vT_ws[(bh * 128 + col) * 2048 + l] = ob;
                }
            }
    }
}

// ---------------------------------------------------------------- attention
// One block (512 thr = 8 waves) per (q_tile=128 rows, h, b). Flash-style.
#define APAD 8
__global__ __launch_bounds__(512) void attn_kernel(
    const unsigned short* __restrict__ q_ws,
    const unsigned short* __restrict__ k_ws,
    const unsigned short* __restrict__ vT_ws,
    unsigned short* __restrict__ aout,
    const int* __restrict__ causal_ptr)
{
    __shared__ unsigned short Ksm[128][128 + APAD];   // aliased as P after S
    __shared__ unsigned short Vsm[128][128 + APAD];   // d-major (V^T)

    const int qt = blockIdx.x, h = blockIdx.y, b = blockIdx.z;
    const int tid = threadIdx.x;
    const int lane = tid & 63, w = tid >> 6;           // w: 0..7
    const int quad = lane >> 4, li = lane & 15;
    const size_t bh = (size_t)(b * 16 + h);
    const unsigned short* Qp = q_ws + bh * 2048 * 128;
    const unsigned short* Kp = k_ws + bh * 2048 * 128;
    const unsigned short* Vp = vT_ws + bh * 128 * 2048;
    const int causal = causal_ptr[0];
    const float scale = 0.08838834764831845f;          // 1/sqrt(128)

    // Q fragments (A-operand) straight from global: rows qt*128 + w*16 + li
    bf16x8 qf[4];
    const int qrow = qt * 128 + w * 16 + li;
    #pragma unroll
    for (int ks = 0; ks < 4; ++ks)
        qf[ks] = *(const bf16x8*)(Qp + (size_t)qrow * 128 + ks * 32 + quad * 8);

    floatx4 O[8] = {};
    float m_i[4], l_i[4];
    #pragma unroll
    for (int r = 0; r < 4; ++r) { m_i[r] = -INFINITY; l_i[r] = 0.f; }

    const int ktEnd = causal ? qt : 15;
    for (int kt = 0; kt <= ktEnd; ++kt) {
        // stage K tile [128 keys][128 d] and V^T tile [128 d][128 keys]
        #pragma unroll
        for (int c = 0; c < 4; ++c) {
            int chunk = c * 512 + tid;            // 0..2047
            int row = chunk >> 4;                 // 0..127
            int cc  = (chunk & 15) * 8;
            *(uint4*)(&Ksm[row][cc]) =
                *(const uint4*)(Kp + (size_t)(kt * 128 + row) * 128 + cc);
            *(uint4*)(&Vsm[row][cc]) =
                *(const uint4*)(Vp + (size_t)row * 2048 + kt * 128 + cc);
        }
        __syncthreads();

        // S = Q K^T  (wave's 16 q-rows x 128 keys)
        floatx4 S[8];
        #pragma unroll
        for (int ct = 0; ct < 8; ++ct) {
            floatx4 s = {};
            #pragma unroll
            for (int ks = 0; ks < 4; ++ks) {
                bf16x8 kf = *(const bf16x8*)(&Ksm[ct * 16 + li][ks * 32 + quad * 8]);
                s = __builtin_amdgcn_mfma_f32_16x16x32_bf16(qf[ks], kf, s, 0, 0, 0);
            }
            S[ct] = s;
        }
        // scale + causal mask (diagonal tile only)
        #pragma unroll
        for (int ct = 0; ct < 8; ++ct)
            #pragma unroll
            for (int r = 0; r < 4; ++r) {
                float sv = S[ct][r] * scale;
                if (causal && kt == qt) {
                    int colL = ct * 16 + li;
                    int rowL = w * 16 + quad * 4 + r;
                    if (colL > rowL) sv = -INFINITY;
                }
                S[ct][r] = sv;
            }

        // online softmax (rows live across 16-lane groups)
        float mnew[4], alpha[4], rs[4];
        unsigned short pv[8][4];
        #pragma unroll
        for (int r = 0; r < 4; ++r) {
            float mx = S[0][r];
            #pragma unroll
            for (int ct = 1; ct < 8; ++ct) mx = fmaxf(mx, S[ct][r]);
            mx = fmaxf(mx, __shfl_xor(mx, 8, 16));
            mx = fmaxf(mx, __shfl_xor(mx, 4, 16));
            mx = fmaxf(mx, __shfl_xor(mx, 2, 16));
            mx = fmaxf(mx, __shfl_xor(mx, 1, 16));
            mnew[r] = fmaxf(m_i[r], mx);
            alpha[r] = __expf(m_i[r] - mnew[r]);
            rs[r] = 0.f;
        }
        #pragma unroll
        for (int ct = 0; ct < 8; ++ct)
            #pragma unroll
            for (int r = 0; r < 4; ++r) {
                float p = __expf(S[ct][r] - mnew[r]);
                rs[r] += p;
                pv[ct][r] = f2bf(p);
            }
        #pragma unroll
        for (int r = 0; r < 4; ++r) {
            float s = rs[r];
            s += __shfl_xor(s, 8, 16);
            s += __shfl_xor(s, 4, 16);
            s += __shfl_xor(s, 2, 16);
            s += __shfl_xor(s, 1, 16);
            l_i[r] = l_i[r] * alpha[r] + s;
            m_i[r] = mnew[r];
        }
        #pragma unroll
        for (int dt = 0; dt < 8; ++dt)
            #pragma unroll
            for (int r = 0; r < 4; ++r)
                O[dt][r] *= alpha[r];

        __syncthreads();   // all waves done reading Ksm before P overwrites it

        // write P (bf16) into Ksm alias; wave's rows are exclusive (w*16..+15)
        #pragma unroll
        for (int ct = 0; ct < 8; ++ct)
            #pragma unroll
            for (int r = 0; r < 4; ++r)
                Ksm[w * 16 + quad * 4 + r][ct * 16 + li] = pv[ct][r];
        // no barrier needed: each wave reads only its own 16 P-rows

        // O += P V
        #pragma unroll
        for (int ks = 0; ks < 4; ++ks) {
            bf16x8 pf = *(const bf16x8*)(&Ksm[w * 16 + li][ks * 32 + quad * 8]);
            #pragma unroll
            for (int dt = 0; dt < 8; ++dt) {
                bf16x8 vf = *(const bf16x8*)(&Vsm[dt * 16 + li][ks * 32 + quad * 8]);
                O[dt] = __builtin_amdgcn_mfma_f32_16x16x32_bf16(pf, vf, O[dt], 0, 0, 0);
            }
        }
        __syncthreads();   // before next iteration restages K/V
    }

    // epilogue: O/l -> bf16 -> aout[b][l][h*128+d]  (row-major [4096,2048])
    float inv_l[4];
    #pragma unroll
    for (int r = 0; r < 4; ++r) inv_l[r] = 1.0f / l_i[r];
    #pragma unroll
    for (int dt = 0; dt < 8; ++dt)
        #pragma unroll
        for (int r = 0; r < 4; ++r) {
            int qr = qt * 128 + w * 16 + quad * 4 + r;
            aout[((size_t)b * 2048 + qr) * 2048 + h * 128 + dt * 16 + li] =
                f2bf(O[dt][r] * inv_l[r]);
        }
}

// ---------------------------------------------------------------- launch
extern "C" void kernel_launch(void* const* d_in, const int* in_sizes, int n_in,
                              void* d_out, int out_size, void* d_ws, size_t ws_size,
                              hipStream_t stream) {
    const float* x     = (const float*)d_in[0];
    const float* w_in  = (const float*)d_in[1];
    const float* b_in  = (const float*)d_in[2];
    const float* w_out = (const float*)d_in[3];
    const float* b_out = (const float*)d_in[4];
    const int* causal  = (const int*)d_in[5];

    char* ws = (char*)d_ws;
    unsigned short* xb    = (unsigned short*)ws; ws += (size_t)4096 * 2048 * 2;
    unsigned short* wb    = (unsigned short*)ws; ws += (size_t)6144 * 2048 * 2;
    unsigned short* wob   = (unsigned short*)ws; ws += (size_t)2048 * 2048 * 2;
    unsigned short* q_ws  = (unsigned short*)ws; ws += (size_t)32 * 2048 * 128 * 2;
    unsigned short* k_ws  = (unsigned short*)ws; ws += (size_t)32 * 2048 * 128 * 2;
    unsigned short* vT_ws = (unsigned short*)ws; ws += (size_t)32 * 2048 * 128 * 2;
    unsigned short* aout  = (unsigned short*)ws; ws += (size_t)4096 * 2048 * 2;

    cast_f32_bf16<<<8192, 256, 0, stream>>>(x, xb, 4096 * 2048);
    cast_f32_bf16<<<12288, 256, 0, stream>>>(w_in, wb, 6144 * 2048);
    cast_f32_bf16<<<4096, 256, 0, stream>>>(w_out, wob, 2048 * 2048);

    gemm_nt<1><<<dim3(48, 32), 256, 0, stream>>>(
        xb, wb, b_in, nullptr, q_ws, k_ws, vT_ws, 4096, 6144, 2048);

    attn_kernel<<<dim3(16, 16, 2), 512, 0, stream>>>(
        q_ws, k_ws, vT_ws, aout, causal);

    gemm_nt<0><<<dim3(16, 32), 256, 0, stream>>>(
        aout, wob, b_out, (float*)d_out, nullptr, nullptr, nullptr,
        4096, 2048, 2048);
}

// Round 2
// 439.074 us; speedup vs baseline: 1.1986x; 1.1986x over previous
//
#include <hip/hip_runtime.h>
#include <hip/hip_bf16.h>
#include <math.h>

typedef __attribute__((ext_vector_type(4))) float floatx4;
typedef __attribute__((ext_vector_type(8))) __bf16 bf16x8;

__device__ __forceinline__ unsigned short f2bf(float f) {
    union { float f; unsigned int u; } v; v.f = f;
    unsigned int u = v.u;
    u += 0x7FFFu + ((u >> 16) & 1u);          // round-to-nearest-even
    return (unsigned short)(u >> 16);
}

// async global->LDS, 16B per lane; lds base must be wave-uniform
__device__ __forceinline__ void gl_lds16(const void* g, void* l) {
    __builtin_amdgcn_global_load_lds(
        (const __attribute__((address_space(1))) void*)g,
        (__attribute__((address_space(3))) void*)l, 16, 0, 0);
}

// ---------------------------------------------------------------- cast kernel
__global__ void cast_f32_bf16(const float* __restrict__ in,
                              unsigned short* __restrict__ out, int n) {
    int i = (blockIdx.x * blockDim.x + threadIdx.x) * 4;
    if (i + 4 <= n) {
        float4 f = *(const float4*)(in + i);
        ushort4 o;
        o.x = f2bf(f.x); o.y = f2bf(f.y); o.z = f2bf(f.z); o.w = f2bf(f.w);
        *(ushort4*)(out + i) = o;
    }
}

// ---------------------------------------------------------------- GEMM (NT)
// C[M,N] = A[M,K] * B[N,K]^T + bias[N]
// MODE 0: store fp32 to Cf.   MODE 1: scatter bf16 to q/k/vT (N==6144 path).
#define BM 128
#define BN 128
#define BK 32

template<int MODE>
__global__ __launch_bounds__(256) void gemm_nt(
    const unsigned short* __restrict__ A,
    const unsigned short* __restrict__ B,
    const float* __restrict__ bias,
    float* __restrict__ Cf,
    unsigned short* __restrict__ q_ws,
    unsigned short* __restrict__ k_ws,
    unsigned short* __restrict__ vT_ws,
    int M, int N, int K)
{
    // UNPADDED: required by global_load_lds (wave-uniform base + lane*16)
    __shared__ unsigned short Asm[BM][BK];   // 8 KB
    __shared__ unsigned short Bsm[BN][BK];   // 8 KB

    const int bx = blockIdx.x, by = blockIdx.y;
    const int m0 = by * BM, n0 = bx * BN;
    const int tid = threadIdx.x;
    const int lane = tid & 63, wid = tid >> 6;
    const int quad = lane >> 4, li = lane & 15;
    const int wy = wid >> 1, wx = wid & 1;

    // staging geometry: each 1KB chunk = 16 rows x 64B; 8 chunks per tile
    const int lrow = lane >> 2;          // 0..15 row within chunk
    const int lcol = (lane & 3) * 8;     // ushort col 0,8,16,24

    floatx4 acc[4][4] = {};

    const int kTiles = K / BK;
    for (int kt = 0; kt < kTiles; ++kt) {
        const int k0 = kt * BK;
        #pragma unroll
        for (int c = 0; c < 2; ++c) {
            const int cidx = wid * 2 + c;            // 0..7
            const int row = cidx * 16 + lrow;        // 0..127
            gl_lds16(A + (size_t)(m0 + row) * K + k0 + lcol,
                     &Asm[0][0] + cidx * 512);
            gl_lds16(B + (size_t)(n0 + row) * K + k0 + lcol,
                     &Bsm[0][0] + cidx * 512);
        }
        __syncthreads();   // drains vmcnt(0) -> LDS tiles complete

        bf16x8 af[4], bfr[4];
        #pragma unroll
        for (int t = 0; t < 4; ++t) {
            af[t]  = *(const bf16x8*)(&Asm[wy * 64 + t * 16 + li][quad * 8]);
            bfr[t] = *(const bf16x8*)(&Bsm[wx * 64 + t * 16 + li][quad * 8]);
        }
        #pragma unroll
        for (int i = 0; i < 4; ++i)
            #pragma unroll
            for (int j = 0; j < 4; ++j)
                acc[i][j] = __builtin_amdgcn_mfma_f32_16x16x32_bf16(
                    af[i], bfr[j], acc[i][j], 0, 0, 0);
        __syncthreads();
    }

    // ---------------- epilogue
    if (MODE == 0) {
        #pragma unroll
        for (int i = 0; i < 4; ++i)
            #pragma unroll
            for (int j = 0; j < 4; ++j) {
                int col = wx * 64 + j * 16 + li;
                float bv = bias[n0 + col];
                #pragma unroll
                for (int r = 0; r < 4; ++r) {
                    int row = wy * 64 + i * 16 + quad * 4 + r;
                    Cf[(size_t)(m0 + row) * N + n0 + col] = acc[i][j][r] + bv;
                }
            }
    } else {
        // N = 6144 layout: bx in [0,48): which = bx>>4, h = bx&15, d = col
        const int which = bx >> 4;
        const int h = bx & 15;
        const int b = by >> 4;
        const int lbase = (by & 15) * BM;
        const size_t bh = (size_t)(b * 16 + h);
        #pragma unroll
        for (int i = 0; i < 4; ++i)
            #pragma unroll
            for (int j = 0; j < 4; ++j) {
                int col = wx * 64 + j * 16 + li;   // == d
                float bv = bias[n0 + col];
                #pragma unroll
                for (int r = 0; r < 4; ++r) {
                    int row = wy * 64 + i * 16 + quad * 4 + r;
                    int l = lbase + row;
                    unsigned short ob = f2bf(acc[i][j][r] + bv);
                    if (which == 0)      q_ws[(bh * 2048 + l) * 128 + col] = ob;
                    else if (which == 1) k_ws[(bh * 2048 + l) * 128 + col] = ob;
                    else                 vT_ws[(bh * 128 + col) * 2048 + l] = ob;
                }
            }
    }
}

// ---------------------------------------------------------------- attention
// One block (1024 thr = 16 waves) per (q-tile PAIR {i, 15-i}, h, b).
// Waves 0..7 own q-tile i, waves 8..15 own q-tile 15-i; K/V staged once
// per k-tile and shared -> uniform 17 tile-computes per block.
#define APAD 8
__global__ __launch_bounds__(1024) void attn_kernel(
    const unsigned short* __restrict__ q_ws,
    const unsigned short* __restrict__ k_ws,
    const unsigned short* __restrict__ vT_ws,
    unsigned short* __restrict__ aout,
    const int* __restrict__ causal_ptr)
{
    __shared__ unsigned short Ksm[128][128 + APAD];    // 34816 B
    __shared__ unsigned short Vsm[128][128 + APAD];    // 34816 B (d-major V^T)
    __shared__ unsigned short Psm[16][16][128 + APAD]; // per-wave P chunk, 69632 B

    const int pairI = blockIdx.x;                 // 0..7
    const int h = blockIdx.y, b = blockIdx.z;
    const int tid = threadIdx.x;
    const int lane = tid & 63, w2 = tid >> 6;     // w2: 0..15
    const int half = w2 >> 3, w = w2 & 7;         // half-block wave id 0..7
    const int quad = lane >> 4, li = lane & 15;
    const size_t bh = (size_t)(b * 16 + h);
    const unsigned short* Qp = q_ws + bh * 2048 * 128;
    const unsigned short* Kp = k_ws + bh * 2048 * 128;
    const unsigned short* Vp = vT_ws + bh * 128 * 2048;
    const int causal = causal_ptr[0];
    const float scale = 0.08838834764831845f;     // 1/sqrt(128)

    const int qt = half ? (15 - pairI) : pairI;   // my q-tile
    const int myEnd = causal ? qt : 15;           // last k-tile I compute
    const int ktEnd = causal ? (15 - pairI) : 15; // last k-tile block stages

    // Q fragments (A-operand) straight from global
    bf16x8 qf[4];
    const int qrow = qt * 128 + w * 16 + li;
    #pragma unroll
    for (int ks = 0; ks < 4; ++ks)
        qf[ks] = *(const bf16x8*)(Qp + (size_t)qrow * 128 + ks * 32 + quad * 8);

    floatx4 O[8] = {};
    float m_i[4], l_i[4];
    #pragma unroll
    for (int r = 0; r < 4; ++r) { m_i[r] = -INFINITY; l_i[r] = 0.f; }

    for (int kt = 0; kt <= ktEnd; ++kt) {
        // stage K tile [128 keys][128 d] and V^T tile [128 d][128 keys]
        #pragma unroll
        for (int c = 0; c < 2; ++c) {
            int chunk = c * 1024 + tid;           // 0..2047
            int row = chunk >> 4;                 // 0..127
            int cc  = (chunk & 15) * 8;
            *(uint4*)(&Ksm[row][cc]) =
                *(const uint4*)(Kp + (size_t)(kt * 128 + row) * 128 + cc);
            *(uint4*)(&Vsm[row][cc]) =
                *(const uint4*)(Vp + (size_t)row * 2048 + kt * 128 + cc);
        }
        __syncthreads();

        if (kt <= myEnd) {
            // S = Q K^T  (wave's 16 q-rows x 128 keys)
            floatx4 S[8];
            #pragma unroll
            for (int ct = 0; ct < 8; ++ct) {
                floatx4 s = {};
                #pragma unroll
                for (int ks = 0; ks < 4; ++ks) {
                    bf16x8 kf = *(const bf16x8*)(&Ksm[ct * 16 + li][ks * 32 + quad * 8]);
                    s = __builtin_amdgcn_mfma_f32_16x16x32_bf16(qf[ks], kf, s, 0, 0, 0);
                }
                S[ct] = s;
            }
            // scale + causal mask (diagonal tile only)
            #pragma unroll
            for (int ct = 0; ct < 8; ++ct)
                #pragma unroll
                for (int r = 0; r < 4; ++r) {
                    float sv = S[ct][r] * scale;
                    if (causal && kt == qt) {
                        int colL = ct * 16 + li;
                        int rowL = w * 16 + quad * 4 + r;
                        if (colL > rowL) sv = -INFINITY;
                    }
                    S[ct][r] = sv;
                }

            // online softmax (rows live across 16-lane groups)
            float mnew[4], alpha[4], rs[4];
            unsigned short pv[8][4];
            #pragma unroll
            for (int r = 0; r < 4; ++r) {
                float mx = S[0][r];
                #pragma unroll
                for (int ct = 1; ct < 8; ++ct) mx = fmaxf(mx, S[ct][r]);
                mx = fmaxf(mx, __shfl_xor(mx, 8, 16));
                mx = fmaxf(mx, __shfl_xor(mx, 4, 16));
                mx = fmaxf(mx, __shfl_xor(mx, 2, 16));
                mx = fmaxf(mx, __shfl_xor(mx, 1, 16));
                mnew[r] = fmaxf(m_i[r], mx);
                alpha[r] = __expf(m_i[r] - mnew[r]);
                rs[r] = 0.f;
            }
            #pragma unroll
            for (int ct = 0; ct < 8; ++ct)
                #pragma unroll
                for (int r = 0; r < 4; ++r) {
                    float p = __expf(S[ct][r] - mnew[r]);
                    rs[r] += p;
                    pv[ct][r] = f2bf(p);
                }
            #pragma unroll
            for (int r = 0; r < 4; ++r) {
                float s = rs[r];
                s += __shfl_xor(s, 8, 16);
                s += __shfl_xor(s, 4, 16);
                s += __shfl_xor(s, 2, 16);
                s += __shfl_xor(s, 1, 16);
                l_i[r] = l_i[r] * alpha[r] + s;
                m_i[r] = mnew[r];
            }
            #pragma unroll
            for (int dt = 0; dt < 8; ++dt)
                #pragma unroll
                for (int r = 0; r < 4; ++r)
                    O[dt][r] *= alpha[r];

            // write P (bf16) into this wave's exclusive Psm chunk
            #pragma unroll
            for (int ct = 0; ct < 8; ++ct)
                #pragma unroll
                for (int r = 0; r < 4; ++r)
                    Psm[w2][quad * 4 + r][ct * 16 + li] = pv[ct][r];
            // no barrier needed: each wave reads only its own chunk

            // O += P V
            #pragma unroll
            for (int ks = 0; ks < 4; ++ks) {
                bf16x8 pf = *(const bf16x8*)(&Psm[w2][li][ks * 32 + quad * 8]);
                #pragma unroll
                for (int dt = 0; dt < 8; ++dt) {
                    bf16x8 vf = *(const bf16x8*)(&Vsm[dt * 16 + li][ks * 32 + quad * 8]);
                    O[dt] = __builtin_amdgcn_mfma_f32_16x16x32_bf16(pf, vf, O[dt], 0, 0, 0);
                }
            }
        }
        __syncthreads();   // before next iteration restages K/V
    }

    // epilogue: O/l -> bf16 -> aout[b][l][h*128+d]  (row-major [4096,2048])
    float inv_l[4];
    #pragma unroll
    for (int r = 0; r < 4; ++r) inv_l[r] = 1.0f / l_i[r];
    #pragma unroll
    for (int dt = 0; dt < 8; ++dt)
        #pragma unroll
        for (int r = 0; r < 4; ++r) {
            int qr = qt * 128 + w * 16 + quad * 4 + r;
            aout[((size_t)b * 2048 + qr) * 2048 + h * 128 + dt * 16 + li] =
                f2bf(O[dt][r] * inv_l[r]);
        }
}

// ---------------------------------------------------------------- launch
extern "C" void kernel_launch(void* const* d_in, const int* in_sizes, int n_in,
                              void* d_out, int out_size, void* d_ws, size_t ws_size,
                              hipStream_t stream) {
    const float* x     = (const float*)d_in[0];
    const float* w_in  = (const float*)d_in[1];
    const float* b_in  = (const float*)d_in[2];
    const float* w_out = (const float*)d_in[3];
    const float* b_out = (const float*)d_in[4];
    const int* causal  = (const int*)d_in[5];

    char* ws = (char*)d_ws;
    unsigned short* xb    = (unsigned short*)ws; ws += (size_t)4096 * 2048 * 2;
    unsigned short* wb    = (unsigned short*)ws; ws += (size_t)6144 * 2048 * 2;
    unsigned short* wob   = (unsigned short*)ws; ws += (size_t)2048 * 2048 * 2;
    unsigned short* q_ws  = (unsigned short*)ws; ws += (size_t)32 * 2048 * 128 * 2;
    unsigned short* k_ws  = (unsigned short*)ws; ws += (size_t)32 * 2048 * 128 * 2;
    unsigned short* vT_ws = (unsigned short*)ws; ws += (size_t)32 * 2048 * 128 * 2;
    unsigned short* aout  = (unsigned short*)ws; ws += (size_t)4096 * 2048 * 2;

    cast_f32_bf16<<<8192, 256, 0, stream>>>(x, xb, 4096 * 2048);
    cast_f32_bf16<<<12288, 256, 0, stream>>>(w_in, wb, 6144 * 2048);
    cast_f32_bf16<<<4096, 256, 0, stream>>>(w_out, wob, 2048 * 2048);

    gemm_nt<1><<<dim3(48, 32), 256, 0, stream>>>(
        xb, wb, b_in, nullptr, q_ws, k_ws, vT_ws, 4096, 6144, 2048);

    attn_kernel<<<dim3(8, 16, 2), 1024, 0, stream>>>(
        q_ws, k_ws, vT_ws, aout, causal);

    gemm_nt<0><<<dim3(16, 32), 256, 0, stream>>>(
        aout, wob, b_out, (float*)d_out, nullptr, nullptr, nullptr,
        4096, 2048, 2048);
}

// Round 5
// 437.774 us; speedup vs baseline: 1.2022x; 1.0030x over previous
//
#include <hip/hip_runtime.h>
#include <hip/hip_bf16.h>
#include <math.h>

typedef __attribute__((ext_vector_type(4))) float floatx4;
typedef __attribute__((ext_vector_type(16))) float floatx16;
typedef __attribute__((ext_vector_type(8))) __bf16 bf16x8;

__device__ __forceinline__ unsigned short f2bf(float f) {
    union { float f; unsigned int u; } v; v.f = f;
    unsigned int u = v.u;
    u += 0x7FFFu + ((u >> 16) & 1u);          // round-to-nearest-even
    return (unsigned short)(u >> 16);
}

__device__ __forceinline__ unsigned int pkbf(float a, float b) {
    return (unsigned int)f2bf(a) | ((unsigned int)f2bf(b) << 16);  // low16=a
}

// async global->LDS, 16B per lane; lds base must be wave-uniform
__device__ __forceinline__ void gl_lds16(const void* g, void* l) {
    __builtin_amdgcn_global_load_lds(
        (const __attribute__((address_space(1))) void*)g,
        (__attribute__((address_space(3))) void*)l, 16, 0, 0);
}

// ---------------------------------------------------------------- cast kernel
__global__ void cast_f32_bf16(const float* __restrict__ in,
                              unsigned short* __restrict__ out, int n) {
    int i = (blockIdx.x * blockDim.x + threadIdx.x) * 4;
    if (i + 4 <= n) {
        float4 f = *(const float4*)(in + i);
        ushort4 o;
        o.x = f2bf(f.x); o.y = f2bf(f.y); o.z = f2bf(f.z); o.w = f2bf(f.w);
        *(ushort4*)(out + i) = o;
    }
}

// ---------------------------------------------------------------- GEMM (NT)
// C[M,N] = A[M,K] * B[N,K]^T + bias[N]
// MODE 0: store fp32 to Cf.   MODE 1: scatter bf16 to q/k/vT (N==6144 path).
#define BM 128
#define BN 128
#define BK 32
#define GROUP_M 8

template<int MODE>
__global__ __launch_bounds__(256) void gemm_nt(
    const unsigned short* __restrict__ A,
    const unsigned short* __restrict__ B,
    const float* __restrict__ bias,
    float* __restrict__ Cf,
    unsigned short* __restrict__ q_ws,
    unsigned short* __restrict__ k_ws,
    unsigned short* __restrict__ vT_ws,
    int M, int N, int K)
{
    // UNPADDED: required by global_load_lds (wave-uniform base + lane*16)
    __shared__ unsigned short Asm[BM][BK];   // 8 KB
    __shared__ unsigned short Bsm[BN][BK];   // 8 KB

    // L2-locality swizzle: 8 consecutive blocks share one B-tile, span 8 A-tiles
    const int id = blockIdx.x + gridDim.x * blockIdx.y;
    const int perGroup = gridDim.x * GROUP_M;
    const int group = id / perGroup;
    const int rem = id % perGroup;
    const int gh = min(GROUP_M, (int)gridDim.y - group * GROUP_M);
    const int by = group * GROUP_M + rem % gh;
    const int bx = rem / gh;

    const int m0 = by * BM, n0 = bx * BN;
    const int tid = threadIdx.x;
    const int lane = tid & 63, wid = tid >> 6;
    const int quad = lane >> 4, li = lane & 15;
    const int wy = wid >> 1, wx = wid & 1;

    // staging geometry: each 1KB chunk = 16 rows x 64B; 8 chunks per tile
    const int lrow = lane >> 2;          // 0..15 row within chunk
    const int lcol = (lane & 3) * 8;     // ushort col 0,8,16,24

    floatx4 acc[4][4] = {};

    const int kTiles = K / BK;
    for (int kt = 0; kt < kTiles; ++kt) {
        const int k0 = kt * BK;
        #pragma unroll
        for (int c = 0; c < 2; ++c) {
            const int cidx = wid * 2 + c;            // 0..7
            const int row = cidx * 16 + lrow;        // 0..127
            gl_lds16(A + (size_t)(m0 + row) * K + k0 + lcol,
                     &Asm[0][0] + cidx * 512);
            gl_lds16(B + (size_t)(n0 + row) * K + k0 + lcol,
                     &Bsm[0][0] + cidx * 512);
        }
        __syncthreads();   // drains vmcnt(0) -> LDS tiles complete

        bf16x8 af[4], bfr[4];
        #pragma unroll
        for (int t = 0; t < 4; ++t) {
            af[t]  = *(const bf16x8*)(&Asm[wy * 64 + t * 16 + li][quad * 8]);
            bfr[t] = *(const bf16x8*)(&Bsm[wx * 64 + t * 16 + li][quad * 8]);
        }
        #pragma unroll
        for (int i = 0; i < 4; ++i)
            #pragma unroll
            for (int j = 0; j < 4; ++j)
                acc[i][j] = __builtin_amdgcn_mfma_f32_16x16x32_bf16(
                    af[i], bfr[j], acc[i][j], 0, 0, 0);
        __syncthreads();
    }

    // ---------------- epilogue
    if (MODE == 0) {
        #pragma unroll
        for (int i = 0; i < 4; ++i)
            #pragma unroll
            for (int j = 0; j < 4; ++j) {
                int col = wx * 64 + j * 16 + li;
                float bv = bias[n0 + col];
                #pragma unroll
                for (int r = 0; r < 4; ++r) {
                    int row = wy * 64 + i * 16 + quad * 4 + r;
                    Cf[(size_t)(m0 + row) * N + n0 + col] = acc[i][j][r] + bv;
                }
            }
    } else {
        // N = 6144 layout: bx in [0,48): which = bx>>4, h = bx&15, d = col
        const int which = bx >> 4;
        const int h = bx & 15;
        const int b = by >> 4;
        const int lbase = (by & 15) * BM;
        const size_t bh = (size_t)(b * 16 + h);
        #pragma unroll
        for (int i = 0; i < 4; ++i)
            #pragma unroll
            for (int j = 0; j < 4; ++j) {
                int col = wx * 64 + j * 16 + li;   // == d
                float bv = bias[n0 + col];
                #pragma unroll
                for (int r = 0; r < 4; ++r) {
                    int row = wy * 64 + i * 16 + quad * 4 + r;
                    int l = lbase + row;
                    unsigned short ob = f2bf(acc[i][j][r] + bv);
                    if (which == 0)      q_ws[(bh * 2048 + l) * 128 + col] = ob;
                    else if (which == 1) k_ws[(bh * 2048 + l) * 128 + col] = ob;
                    else                 vT_ws[(bh * 128 + col) * 2048 + l] = ob;
                }
            }
    }
}

// ---------------------------------------------------------------- attention
// 256 thr = 4 waves per block; block = one 128-row q-tile of one (b,h).
// Wave owns 32 q-rows. 32x32x16 MFMA. S^T = K*Q^T (softmax lane-local),
// O^T = V^T * P^T with P transposed S->B-frag via register shuffles.
#define AP 8
__global__ __launch_bounds__(256, 2) void attn_kernel(
    const unsigned short* __restrict__ q_ws,
    const unsigned short* __restrict__ k_ws,
    const unsigned short* __restrict__ vT_ws,
    unsigned short* __restrict__ aout,
    const int* __restrict__ causal_ptr)
{
    __shared__ unsigned short Ksm[128][128 + AP];   // 34 KB (reused for O epilogue)
    __shared__ unsigned short Vsm[128][128 + AP];   // 34 KB, d-major (V^T)

    // balanced mapping: blocks c and c+256 sum to 17 tile-computes
    const int ord = blockIdx.x;
    int qt, bhid;
    if (ord < 256) { qt = ord >> 5;              bhid = ord & 31; }
    else           { qt = 15 - ((ord - 256) >> 5); bhid = ord & 31; }
    const int b = bhid >> 4, h = bhid & 15;

    const int tid = threadIdx.x;
    const int lane = tid & 63, w = tid >> 6;       // 4 waves
    const int lq = lane & 31;                      // q-col / row-in-tile
    const int half = lane >> 5;
    const size_t bh = (size_t)(b * 16 + h);
    const unsigned short* Qp = q_ws + bh * 2048 * 128;
    const unsigned short* Kp = k_ws + bh * 2048 * 128;
    const unsigned short* Vp = vT_ws + bh * 128 * 2048;
    const int causal = causal_ptr[0];
    const float scale = 0.08838834764831845f;      // 1/sqrt(128)

    // Q^T B-operand frags (persist): qf[s][j] = Q[qg][16s + 8*half + j]
    const int qg = qt * 128 + w * 32 + lq;
    bf16x8 qf[8];
    #pragma unroll
    for (int s = 0; s < 8; ++s)
        qf[s] = *(const bf16x8*)(Qp + (size_t)qg * 128 + s * 16 + half * 8);

    floatx16 O[4] = {};
    float m_i = -INFINITY, l_i = 0.f;

    const int myEnd = causal ? qt : 15;
    for (int kt = 0; kt <= myEnd; ++kt) {
        // stage K [key][d] and V^T [d][key] tiles: 2048 x 16B chunks
        // (FIX: was 1024 chunks / 8 per row -> cols 64..127 never staged)
        #pragma unroll
        for (int c = 0; c < 8; ++c) {
            int chunk = c * 256 + tid;            // 0..2047
            int row = chunk >> 4;                 // 0..127
            int cc  = (chunk & 15) * 8;           // ushort col 0..120
            *(uint4*)(&Ksm[row][cc]) =
                *(const uint4*)(Kp + (size_t)(kt * 128 + row) * 128 + cc);
            *(uint4*)(&Vsm[row][cc]) =
                *(const uint4*)(Vp + (size_t)row * 2048 + kt * 128 + cc);
        }
        __syncthreads();

        // S^T[key][q]: 4 key-groups of 32; A = K rows, B = Q^T
        floatx16 S[4] = {};
        #pragma unroll
        for (int ct = 0; ct < 4; ++ct)
            #pragma unroll
            for (int s = 0; s < 8; ++s) {
                bf16x8 kf = *(const bf16x8*)(&Ksm[ct * 32 + lq][s * 16 + half * 8]);
                S[ct] = __builtin_amdgcn_mfma_f32_32x32x16_bf16(kf, qf[s], S[ct], 0, 0, 0);
            }

        // scale + causal mask; row stats are LANE-LOCAL (col of S^T = q)
        const bool diag = causal && (kt == qt);
        float mx = -INFINITY;
        #pragma unroll
        for (int ct = 0; ct < 4; ++ct)
            #pragma unroll
            for (int r = 0; r < 16; ++r) {
                float sv = S[ct][r] * scale;
                if (diag) {
                    int key = 32 * ct + (r & 3) + 8 * (r >> 2) + 4 * half;
                    if (kt * 128 + key > qg) sv = -INFINITY;
                }
                S[ct][r] = sv;
                mx = fmaxf(mx, sv);
            }
        mx = fmaxf(mx, __shfl_xor(mx, 32, 64));   // combine key-halves
        float m_new = fmaxf(m_i, mx);
        // armor: if all keys masked (shouldn't happen), keep finite exp base
        float m_use = (m_new == -INFINITY) ? 0.f : m_new;
        float alpha = __expf(m_i - m_use);

        float rs = 0.f;
        #pragma unroll
        for (int ct = 0; ct < 4; ++ct)
            #pragma unroll
            for (int r = 0; r < 16; ++r) {
                float p = __expf(S[ct][r] - m_use);
                S[ct][r] = p;
                rs += p;
            }
        rs += __shfl_xor(rs, 32, 64);
        l_i = l_i * alpha + rs;
        m_i = m_new;
        #pragma unroll
        for (int dt = 0; dt < 4; ++dt)
            #pragma unroll
            for (int r = 0; r < 16; ++r)
                O[dt][r] *= alpha;

        // P^T -> B-operand frags via register half-swap (no LDS round-trip)
        bf16x8 pfr[8];
        #pragma unroll
        for (int ct = 0; ct < 4; ++ct)
            #pragma unroll
            for (int h2 = 0; h2 < 2; ++h2) {
                int base = 8 * h2;
                unsigned int pk0 = pkbf(S[ct][base + 0], S[ct][base + 1]);
                unsigned int pk1 = pkbf(S[ct][base + 2], S[ct][base + 3]);
                unsigned int pk2 = pkbf(S[ct][base + 4], S[ct][base + 5]);
                unsigned int pk3 = pkbf(S[ct][base + 6], S[ct][base + 7]);
                unsigned int x0 = __shfl_xor((int)pk0, 32, 64);
                unsigned int x1 = __shfl_xor((int)pk1, 32, 64);
                unsigned int x2 = __shfl_xor((int)pk2, 32, 64);
                unsigned int x3 = __shfl_xor((int)pk3, 32, 64);
                union { unsigned int u[4]; bf16x8 v; } fr;
                fr.u[0] = half ? x2 : pk0;
                fr.u[1] = half ? x3 : pk1;
                fr.u[2] = half ? pk2 : x0;
                fr.u[3] = half ? pk3 : x1;
                pfr[ct * 2 + h2] = fr.v;
            }

        // O^T[d][q] += V^T * P^T; A = V^T rows (d), B = pfr
        #pragma unroll
        for (int dt = 0; dt < 4; ++dt)
            #pragma unroll
            for (int s = 0; s < 8; ++s) {
                bf16x8 vf = *(const bf16x8*)(&Vsm[dt * 32 + lq][s * 16 + half * 8]);
                O[dt] = __builtin_amdgcn_mfma_f32_32x32x16_bf16(vf, pfr[s], O[dt], 0, 0, 0);
            }
        __syncthreads();   // before next tile restages K/V
    }

    // epilogue: normalize, transpose O^T->[q][d] via Ksm, coalesced store
    const float invl = 1.0f / l_i;
    #pragma unroll
    for (int dt = 0; dt < 4; ++dt)
        #pragma unroll
        for (int g = 0; g < 4; ++g) {
            int dbase = dt * 32 + g * 8 + half * 4;
            ushort4 o4;
            o4.x = f2bf(O[dt][g * 4 + 0] * invl);
            o4.y = f2bf(O[dt][g * 4 + 1] * invl);
            o4.z = f2bf(O[dt][g * 4 + 2] * invl);
            o4.w = f2bf(O[dt][g * 4 + 3] * invl);
            *(ushort4*)(&Ksm[w * 32 + lq][dbase]) = o4;
        }
    __syncthreads();
    #pragma unroll
    for (int c = 0; c < 8; ++c) {
        int chunk = c * 256 + tid;                // 0..2047
        int row = chunk >> 4;                     // 0..127 (q within tile)
        int dc = (chunk & 15) * 8;
        uint4 v = *(const uint4*)(&Ksm[row][dc]);
        *(uint4*)(aout + ((size_t)b * 2048 + qt * 128 + row) * 2048 + h * 128 + dc) = v;
    }
}

// ---------------------------------------------------------------- launch
extern "C" void kernel_launch(void* const* d_in, const int* in_sizes, int n_in,
                              void* d_out, int out_size, void* d_ws, size_t ws_size,
                              hipStream_t stream) {
    const float* x     = (const float*)d_in[0];
    const float* w_in  = (const float*)d_in[1];
    const float* b_in  = (const float*)d_in[2];
    const float* w_out = (const float*)d_in[3];
    const float* b_out = (const float*)d_in[4];
    const int* causal  = (const int*)d_in[5];

    char* ws = (char*)d_ws;
    unsigned short* xb    = (unsigned short*)ws; ws += (size_t)4096 * 2048 * 2;
    unsigned short* wb    = (unsigned short*)ws; ws += (size_t)6144 * 2048 * 2;
    unsigned short* wob   = (unsigned short*)ws; ws += (size_t)2048 * 2048 * 2;
    unsigned short* q_ws  = (unsigned short*)ws; ws += (size_t)32 * 2048 * 128 * 2;
    unsigned short* k_ws  = (unsigned short*)ws; ws += (size_t)32 * 2048 * 128 * 2;
    unsigned short* vT_ws = (unsigned short*)ws; ws += (size_t)32 * 2048 * 128 * 2;
    unsigned short* aout  = (unsigned short*)ws; ws += (size_t)4096 * 2048 * 2;

    cast_f32_bf16<<<8192, 256, 0, stream>>>(x, xb, 4096 * 2048);
    cast_f32_bf16<<<12288, 256, 0, stream>>>(w_in, wb, 6144 * 2048);
    cast_f32_bf16<<<4096, 256, 0, stream>>>(w_out, wob, 2048 * 2048);

    gemm_nt<1><<<dim3(48, 32), 256, 0, stream>>>(
        xb, wb, b_in, nullptr, q_ws, k_ws, vT_ws, 4096, 6144, 2048);

    attn_kernel<<<512, 256, 0, stream>>>(
        q_ws, k_ws, vT_ws, aout, causal);

    gemm_nt<0><<<dim3(16, 32), 256, 0, stream>>>(
        aout, wob, b_out, (float*)d_out, nullptr, nullptr, nullptr,
        4096, 2048, 2048);
}